// Round 8
// baseline (229.810 us; speedup 1.0000x reference)
//
#include <hip/hip_runtime.h>
#include <hip/hip_bf16.h>
#include <stdint.h>

typedef unsigned short u16;
typedef __attribute__((ext_vector_type(8))) short short8;
typedef __attribute__((ext_vector_type(4))) float f32x4;
typedef __attribute__((ext_vector_type(16))) float f32x16;

__device__ __forceinline__ u16 f2bf(float f){
  union { __hip_bfloat16 h; u16 u; } v; v.h = __float2bfloat16(f); return v.u;
}
__device__ __forceinline__ float bf2f(u16 h){
  union { uint32_t u; float f; } v; v.u = ((uint32_t)h) << 16;
  return v.f;
}
__device__ __forceinline__ f32x4 mfma16(short8 a, short8 b, f32x4 c){
  return __builtin_amdgcn_mfma_f32_16x16x32_bf16(a, b, c, 0, 0, 0);
}
__device__ __forceinline__ f32x16 mfma32(short8 a, short8 b, f32x16 c){
  return __builtin_amdgcn_mfma_f32_32x32x16_bf16(a, b, c, 0, 0, 0);
}
__device__ __forceinline__ void gl_lds16(const u16* g, u16* l){
  __builtin_amdgcn_global_load_lds((const __attribute__((address_space(1))) void*)g,
                                   (__attribute__((address_space(3))) void*)l, 16, 0, 0);
}
template<int N> __device__ __forceinline__ void waitvm(){
  if constexpr (N==0) asm volatile("s_waitcnt vmcnt(0)" ::: "memory");
  else if constexpr (N==4) asm volatile("s_waitcnt vmcnt(4)" ::: "memory");
  else if constexpr (N==8) asm volatile("s_waitcnt vmcnt(8)" ::: "memory");
  else static_assert(N==0 || N==4 || N==8, "unsupported vmcnt");
}
__device__ __forceinline__ void phase_sep(){
  __builtin_amdgcn_sched_barrier(0);
  __builtin_amdgcn_s_barrier();
  __builtin_amdgcn_sched_barrier(0);
}
__device__ __forceinline__ uint32_t cvtpk(float lo, float hi){
  uint32_t r;
  asm("v_cvt_pk_bf16_f32 %0, %1, %2" : "=v"(r) : "v"(lo), "v"(hi));
  return r;
}

// ---------------- f32 -> bf16 convert (x) ----------------
__global__ __launch_bounds__(256) void cvt_x(const float* __restrict__ s,
                                             u16* __restrict__ d, int n4){
  const int i = blockIdx.x*256 + threadIdx.x;
  if (i >= n4) return;
  const float4 v = ((const float4*)s)[i];
  ushort4 pk;
  pk.x = f2bf(v.x); pk.y = f2bf(v.y); pk.z = f2bf(v.z); pk.w = f2bf(v.w);
  ((ushort4*)d)[i] = pk;
}

// ---------------- f32 [R][C] -> bf16 [C][R] transpose ----------------
__global__ __launch_bounds__(256) void transpose_cvt(const float* __restrict__ src,
    u16* __restrict__ dst, int R, int C)
{
  __shared__ float tile[32][33];
  const int tx = threadIdx.x, ty = threadIdx.y;
  const int c0 = blockIdx.x << 5, r0 = blockIdx.y << 5;
  #pragma unroll
  for (int i=0;i<4;i++)
    tile[ty + (i<<3)][tx] = src[(size_t)(r0 + ty + (i<<3))*C + c0 + tx];
  __syncthreads();
  #pragma unroll
  for (int i=0;i<4;i++)
    dst[(size_t)(c0 + ty + (i<<3))*R + r0 + tx] = f2bf(tile[tx][ty + (i<<3)]);
}

// ---------------- V transpose: qkv v-slice [S][128] -> vT [128][S] per (b,kv) ----------------
__global__ __launch_bounds__(256) void v_transpose(const u16* __restrict__ qkv,
    u16* __restrict__ vT)
{
  __shared__ u16 tile[32][33];
  const int tx = threadIdx.x, ty = threadIdx.y;
  const int s0 = blockIdx.x << 5, d0 = blockIdx.y << 5;
  const int bk = blockIdx.z; const int b = bk >> 2, kv = bk & 3;
  const u16* src = qkv + (size_t)b*2048*3072 + 2560 + kv*128;
  #pragma unroll
  for (int i=0;i<4;i++)
    tile[ty + (i<<3)][tx] = src[(size_t)(s0 + ty + (i<<3))*3072 + d0 + tx];
  __syncthreads();
  u16* dst = vT + (size_t)((b<<2)+kv)*128*2048;
  #pragma unroll
  for (int i=0;i<4;i++)
    dst[(size_t)(d0 + ty + (i<<3))*2048 + s0 + tx] = tile[tx][ty + (i<<3)];
}

// ---------------- RMSNorm over each 128-wide head row of q and k ----------------
// q heads additionally scaled by 1/sqrt(128)*log2(e) (softmax in exp2 domain).
__global__ __launch_bounds__(256) void rmsnorm_qk(u16* __restrict__ qkv,
    const float* __restrict__ qw, const float* __restrict__ kw)
{
  const int lane = threadIdx.x & 63;
  const int rid = blockIdx.x*4 + (threadIdx.x >> 6);   // 0..81919
  const int row = rid / 20;
  const int slot = rid % 20;                            // 0..15 q heads, 16..19 k heads
  u16* p = qkv + (size_t)row*3072 + slot*128 + (lane<<1);
  const u16 r0 = p[0], r1 = p[1];
  const float a = bf2f(r0), c = bf2f(r1);
  float ss = a*a + c*c;
  #pragma unroll
  for (int off=1; off<64; off<<=1) ss += __shfl_xor(ss, off);
  float sc = rsqrtf(ss*(1.0f/128.0f) + 1e-6f);
  if (slot < 16) sc *= 0.1275187952317199f;  // (1/sqrt(128)) * log2(e)
  const float* wp = (slot < 16) ? qw : kw;
  const float w0 = wp[lane<<1], w1 = wp[(lane<<1)+1];
  p[0] = f2bf(a*sc*w0);
  p[1] = f2bf(c*sc*w1);
}

// ---------------- 8-phase 256x256 bf16 GEMM (unchanged from R5) ----------------
template<int CBF16>
__global__ __launch_bounds__(512, 2) void gemm8(const u16* __restrict__ A,
    const u16* __restrict__ BT, void* __restrict__ Cp,
    int M, int N, int K, int ldc)
{
  __shared__ u16 lds[65536];           // 8 slots x 8192 u16 (16 KB)
  const int tid = threadIdx.x;
  const int w = tid >> 6, lane = tid & 63;
  const int l15 = lane & 15, lg = lane >> 4;
  const int wm = w >> 2, wn = w & 3;
  const int nbx = N >> 8;
  const int nwg = gridDim.x;
  int bid = blockIdx.x;
  bid = (bid & 7) * (nwg >> 3) + (bid >> 3);   // bijective XCD swizzle (nwg%8==0)
  const int m0 = (bid / nbx) << 8;
  const int n0 = (bid % nbx) << 8;

  const u16* gA0 = A  + (size_t)m0*K;
  const u16* gA1 = gA0 + (size_t)128*K;
  const u16* gB0 = BT + (size_t)n0*K;
  const u16* gB1 = gB0 + (size_t)128*K;

  auto slot = [&](int d, int s)->u16*{ return lds + (((d<<2)+s)<<13); };

  auto stage_half = [&](const u16* gbase, int kt, u16* sbase){
    #pragma unroll
    for (int i=0;i<2;i++){
      const int p = (i<<9) + tid;
      const int row = p>>3, sg = (p&7) ^ (row&7);
      gl_lds16(gbase + (size_t)row*K + (kt<<6) + (sg<<3), sbase + (p<<3));
    }
  };
  auto frag_at = [&](const u16* buf, int lrow, int kk)->short8{
    const int s = ((kk<<2)+lg) ^ (lrow&7);
    return *(const short8*)(buf + (((lrow<<3)+s)<<3));
  };

  short8 af[4][2], bfe[2][2], bfo[2][2];
  f32x4 acc[8][4];
  #pragma unroll
  for (int m=0;m<8;m++)
    #pragma unroll
    for (int n=0;n<4;n++) acc[m][n] = (f32x4){0.f,0.f,0.f,0.f};

  const int bh = 2 + (wn>>1);          // my B-half slot id
  const int brow0 = ((wn&1)<<6) + l15; // base local row in B slot

  auto rd_a = [&](const u16* buf, int mq){
    #pragma unroll
    for (int m=0;m<4;m++)
      #pragma unroll
      for (int kk=0;kk<2;kk++)
        af[m][kk] = frag_at(buf, (mq<<6) + (m<<4) + l15, kk);
  };
  auto rd_b = [&](const u16* buf, int nq, short8 (*dst)[2]){
    #pragma unroll
    for (int n=0;n<2;n++)
      #pragma unroll
      for (int kk=0;kk<2;kk++)
        dst[n][kk] = frag_at(buf, brow0 + (nq<<5) + (n<<4), kk);
  };
  auto do_mfma = [&](int mb, int nb, short8 (*bf)[2]){
    __builtin_amdgcn_s_setprio(1);
    #pragma unroll
    for (int m=0;m<4;m++)
      #pragma unroll
      for (int n=0;n<2;n++)
        #pragma unroll
        for (int kk=0;kk<2;kk++)
          acc[mb+m][nb+n] = mfma16(af[m][kk], bf[n][kk], acc[mb+m][nb+n]);
    __builtin_amdgcn_s_setprio(0);
  };

  stage_half(gA0, 0, slot(0,0)); stage_half(gA1, 0, slot(0,1));
  stage_half(gB0, 0, slot(0,2)); stage_half(gB1, 0, slot(0,3));
  stage_half(gA0, 1, slot(1,0)); stage_half(gA1, 1, slot(1,1));
  waitvm<4>();
  phase_sep();

  const int niter = K >> 7;            // two K-tiles (BK=64) per iteration
  for (int i=0; i<niter; ++i){
    const bool full = (i+1 < niter);
    const int t1 = 2*i+1;
    rd_a(slot(0,wm), 0); rd_b(slot(0,bh), 0, bfe);
    stage_half(gB0, t1, slot(1,2)); stage_half(gB1, t1, slot(1,3));
    phase_sep();
    do_mfma(0, 0, bfe);
    phase_sep();
    rd_b(slot(0,bh), 1, bfo);
    phase_sep();
    do_mfma(0, 2, bfo);
    phase_sep();
    rd_a(slot(0,wm), 1);
    phase_sep();
    do_mfma(4, 2, bfo);
    phase_sep();
    rd_b(slot(0,bh), 0, bfe);
    if (full){ stage_half(gA0, t1+1, slot(0,0)); stage_half(gA1, t1+1, slot(0,1)); }
    phase_sep();
    do_mfma(4, 0, bfe);
    if (full) waitvm<4>(); else waitvm<0>();
    phase_sep();
    rd_a(slot(1,wm), 0); rd_b(slot(1,bh), 0, bfe);
    if (full){ stage_half(gB0, t1+1, slot(0,2)); stage_half(gB1, t1+1, slot(0,3)); }
    phase_sep();
    do_mfma(0, 0, bfe);
    phase_sep();
    rd_b(slot(1,bh), 1, bfo);
    phase_sep();
    do_mfma(0, 2, bfo);
    phase_sep();
    rd_a(slot(1,wm), 1);
    phase_sep();
    do_mfma(4, 2, bfo);
    phase_sep();
    rd_b(slot(1,bh), 0, bfe);
    if (full){ stage_half(gA0, t1+2, slot(1,0)); stage_half(gA1, t1+2, slot(1,1)); }
    phase_sep();
    do_mfma(4, 0, bfe);
    if (full) waitvm<4>();
    phase_sep();
  }

  #pragma unroll
  for (int m=0;m<8;m++){
    #pragma unroll
    for (int n=0;n<4;n++){
      const int col = n0 + (wn<<6) + (n<<4) + l15;
      #pragma unroll
      for (int r=0;r<4;r++){
        const int row = m0 + (wm<<7) + (m<<4) + (lg<<2) + r;
        if (CBF16) ((u16*)Cp)[(size_t)row*ldc + col] = f2bf(acc[m][n][r]);
        else       ((float*)Cp)[(size_t)row*ldc + col] = acc[m][n][r];
      }
    }
  }
}

// ---------------- causal GQA flash attention v4: packed H+L columns ----------------
// grid (16,16,2), 256 thr / 4 waves. Block p_eff handles high q-tile
// hq0=(31-p)*64 AND low q-tile lq0=p*64; each wave packs 16 H rows (lanes/cols
// 0-15) + 16 L rows (cols 16-31) into one 32-col QK^T -> every wave active
// every iteration; nt = 32-p. p_eff = b ? 15-bx : bx so CU-mates (bid, bid+256)
// run 32-p and 17+p iters with overlapping lifetimes. K AND V double-buffered
// (64 KB, 2 blocks/CU); stage(t+2) after compute barrier; one vmcnt(8) per
// iteration (drain only at tail). P in-register via cvt_pk+permlane (T12).
__global__ __launch_bounds__(256, 2) void attn_kernel(const u16* __restrict__ qkv,
    const u16* __restrict__ vT, u16* __restrict__ aout)
{
  __shared__ u16 Klds[2][8192];   // [row 64][slot 16] 16B units, slot = d0 ^ (row&15)
  __shared__ u16 Vlds[2][8192];   // [rp=d/2][sl 16], sl = ((d&1)<<3 | k8) ^ (rp&15)
  const int tid = threadIdx.x;
  const int w = tid >> 6, lane = tid & 63;
  const int l31 = lane & 31, hi = lane >> 5;
  const int bx = blockIdx.x, h = blockIdx.y, b = blockIdx.z;
  const int p_eff = b ? (15 - bx) : bx;
  const int kvh = h >> 2;
  const int hq0 = (31 - p_eff) << 6, lq0 = p_eff << 6;
  const int nt = 32 - p_eff;
  // this lane's packed q-row (cols 0-15 = H, 16-31 = L)
  const int qrow = (l31 < 16) ? (hq0 + (w<<4) + l31) : (lq0 + (w<<4) + l31 - 16);

  const u16* qkvb = qkv + (size_t)b*2048*3072;
  short8 qf[8];
  {
    const u16* qp = qkvb + (size_t)qrow*3072 + h*128 + hi*8;
    #pragma unroll
    for (int kk=0;kk<8;kk++) qf[kk] = *(const short8*)(qp + kk*16);
  }
  f32x16 oacc[4];
  #pragma unroll
  for (int d=0;d<4;d++)
    #pragma unroll
    for (int r=0;r<16;r++) oacc[d][r] = 0.f;
  float m_run = -__builtin_inff(), lsum = 0.f;

  const u16* kb_ = qkvb + 2048 + kvh*128;
  const u16* vb_ = vT + (size_t)((b<<2)+kvh)*128*2048;

  auto stageKV = [&](int t, int buf){
    #pragma unroll
    for (int i=0;i<4;i++){
      const int u = (i<<8) + tid;            // 0..1023
      const int row = u>>4, d0 = (u&15) ^ (row&15);
      gl_lds16(kb_ + (size_t)((t<<6)+row)*3072 + (d0<<3), &Klds[buf][u<<3]);
    }
    #pragma unroll
    for (int i=0;i<4;i++){
      const int u = (i<<8) + tid;
      const int rp = u>>4, z = (u&15) ^ (rp&15);
      const int d = (rp<<1) + (z>>3), k8 = z&7;
      gl_lds16(vb_ + (size_t)d*2048 + (t<<6) + (k8<<3), &Vlds[buf][u<<3]);
    }
  };

  stageKV(0, 0);
  if (nt > 1) stageKV(1, 1);
  for (int t=0; t<nt; ++t){
    const int kbuf = t & 1;
    if (t+1 < nt) waitvm<8>(); else waitvm<0>();   // K/V(t) landed
    phase_sep();
    const int t0 = t<<6;
    // ---- S^T = K Q : lane holds 32 scores for its packed q-row
    f32x16 s0, s1;
    #pragma unroll
    for (int r=0;r<16;r++){ s0[r] = 0.f; s1[r] = 0.f; }
    #pragma unroll
    for (int kk=0;kk<8;kk++){
      const int d0 = (kk<<1) + hi;
      const short8 k0 = *(const short8*)&Klds[kbuf][((l31<<4) + (d0 ^ (l31&15)))<<3];
      s0 = mfma32(k0, qf[kk], s0);
      const int r1 = 32 + l31;
      const short8 k1 = *(const short8*)&Klds[kbuf][((r1<<4) + (d0 ^ (r1&15)))<<3];
      s1 = mfma32(k1, qf[kk], s1);
    }
    // ---- causal mask (per-lane; k-local = (r&3)+8*(r>>2)+4*hi [+32])
    {
      const int qrel = qrow - t0;
      #pragma unroll
      for (int r=0;r<16;r++){
        const int kloc = (r&3) + ((r>>2)<<3) + (hi<<2);
        if (kloc      > qrel) s0[r] = -__builtin_inff();
        if (kloc + 32 > qrel) s1[r] = -__builtin_inff();
      }
    }
    // ---- online softmax (defer-max, exp2 domain)
    float t8[8];
    #pragma unroll
    for (int i=0;i<8;i++) t8[i] = fmaxf(fmaxf(s0[i], s0[i+8]), fmaxf(s1[i], s1[i+8]));
    #pragma unroll
    for (int i=0;i<4;i++) t8[i] = fmaxf(t8[i], t8[i+4]);
    float mx = fmaxf(fmaxf(t8[0],t8[1]), fmaxf(t8[2],t8[3]));
    mx = fmaxf(mx, __shfl_xor(mx, 32));
    const bool noskip = !__all(mx - m_run <= 8.0f);
    const float mnew = noskip ? fmaxf(m_run, mx) : m_run;
    float rs = 0.f;
    #pragma unroll
    for (int i=0;i<16;i++){
      s0[i] = __builtin_amdgcn_exp2f(s0[i] - mnew);
      s1[i] = __builtin_amdgcn_exp2f(s1[i] - mnew);
      rs += s0[i] + s1[i];
    }
    rs += __shfl_xor(rs, 32);
    if (noskip){
      const float corr = __builtin_amdgcn_exp2f(m_run - mnew);
      m_run = mnew;
      lsum = lsum*corr + rs;
      #pragma unroll
      for (int r=0;r<16;r++){
        const float cr = __shfl(corr, (r&3) + ((r>>2)<<3) + (hi<<2));
        #pragma unroll
        for (int db=0;db<4;db++) oacc[db][r] *= cr;
      }
    } else {
      lsum += rs;
    }
    // ---- T12: PV A-frags in-register via cvt_pk + permlane32_swap
    uint32_t paw[4][4];
    #pragma unroll
    for (int kk=0;kk<4;kk++){
      const int base = (kk&1)<<3;
      float v0,v1,v2,v3,v4,v5,v6,v7;
      if (kk<2){ v0=s0[base+0]; v1=s0[base+1]; v2=s0[base+2]; v3=s0[base+3];
                 v4=s0[base+4]; v5=s0[base+5]; v6=s0[base+6]; v7=s0[base+7]; }
      else     { v0=s1[base+0]; v1=s1[base+1]; v2=s1[base+2]; v3=s1[base+3];
                 v4=s1[base+4]; v5=s1[base+5]; v6=s1[base+6]; v7=s1[base+7]; }
      uint32_t a0 = cvtpk(v0, v1), a1 = cvtpk(v2, v3);
      uint32_t b0 = cvtpk(v4, v5), b1 = cvtpk(v6, v7);
      asm volatile("v_permlane32_swap_b32 %0, %1" : "+v"(a0), "+v"(b0));
      asm volatile("v_permlane32_swap_b32 %0, %1" : "+v"(a1), "+v"(b1));
      paw[kk][0] = a0; paw[kk][1] = a1; paw[kk][2] = b0; paw[kk][3] = b1;
    }
    // ---- O += P V
    #pragma unroll
    for (int kk=0;kk<4;kk++){
      union { uint32_t w[4]; short8 v; } pu;
      pu.w[0]=paw[kk][0]; pu.w[1]=paw[kk][1]; pu.w[2]=paw[kk][2]; pu.w[3]=paw[kk][3];
      const short8 pa = pu.v;
      #pragma unroll
      for (int db=0;db<4;db++){
        const int d = (db<<5) + l31, rp = d>>1;
        const int sl = (((d&1)<<3) | ((kk<<1)+hi)) ^ (rp&15);
        const short8 vv = *(const short8*)&Vlds[kbuf][((rp<<4)+sl)<<3];
        oacc[db] = mfma32(pa, vv, oacc[db]);
      }
    }
    phase_sep();                             // all reads of buf(t) done
    if (t+2 < nt) stageKV(t+2, kbuf);        // restage just-freed buffer
  }

  // ---- epilogue: normalize rows, store
  const float inv = 1.0f / lsum;
  #pragma unroll
  for (int r=0;r<16;r++){
    const int qp_ = (r&3) + ((r>>2)<<3) + (hi<<2);       // packed q idx 0..31
    const float ivr = __shfl(inv, qp_);
    const int grow = (qp_ < 16) ? (hq0 + (w<<4) + qp_) : (lq0 + (w<<4) + qp_ - 16);
    u16* op = aout + (size_t)(b*2048 + grow)*2048 + h*128 + l31;
    #pragma unroll
    for (int db=0;db<4;db++)
      op[db<<5] = f2bf(oacc[db][r] * ivr);
  }
}

extern "C" void kernel_launch(void* const* d_in, const int* in_sizes, int n_in,
                              void* d_out, int out_size, void* d_ws, size_t ws_size,
                              hipStream_t stream) {
  const float* x  = (const float*)d_in[0];
  const float* wq = (const float*)d_in[1];
  const float* wk = (const float*)d_in[2];
  const float* wv = (const float*)d_in[3];
  const float* wo = (const float*)d_in[4];
  const float* qw = (const float*)d_in[5];
  const float* kw = (const float*)d_in[6];
  char* ws = (char*)d_ws;
  u16* xbf   = (u16*)(ws);                 // 16 MB; reused as attn_out
  u16* wqkvT = (u16*)(ws + 16777216);      // 12 MB: [3072][2048] = wqT|wkT|wvT
  u16* woT   = (u16*)(ws + 29360128);      // 8 MB:  [2048][2048]
  u16* qkv   = (u16*)(ws + 37748736);      // 24 MB: [4096][3072] q|k|v
  u16* vT    = (u16*)(ws + 62914560);      // 4 MB:  [8][128][2048]
  float* out = (float*)d_out;

  dim3 tb(32,8);
  cvt_x<<<8192, 256, 0, stream>>>(x, xbf, 2097152);
  transpose_cvt<<<dim3(64,64), tb, 0, stream>>>(wq, wqkvT,             2048, 2048);
  transpose_cvt<<<dim3(16,64), tb, 0, stream>>>(wk, wqkvT + 2048*2048, 2048, 512);
  transpose_cvt<<<dim3(16,64), tb, 0, stream>>>(wv, wqkvT + 2560*2048, 2048, 512);
  transpose_cvt<<<dim3(64,64), tb, 0, stream>>>(wo, woT,               2048, 2048);
  gemm8<1><<<192, 512, 0, stream>>>(xbf, wqkvT, qkv, 4096, 3072, 2048, 3072);
  rmsnorm_qk<<<20480, 256, 0, stream>>>(qkv, qw, kw);
  v_transpose<<<dim3(64,4,8), tb, 0, stream>>>(qkv, vT);
  attn_kernel<<<dim3(16,16,2), 256, 0, stream>>>(qkv, vT, xbf);
  gemm8<0><<<128, 512, 0, stream>>>(xbf, woT, out, 4096, 2048, 2048, 2048);
}

// Round 9
// 196.624 us; speedup vs baseline: 1.1688x; 1.1688x over previous
//
#include <hip/hip_runtime.h>
#include <hip/hip_bf16.h>
#include <stdint.h>

typedef unsigned short u16;
typedef __attribute__((ext_vector_type(8))) short short8;
typedef __attribute__((ext_vector_type(4))) float f32x4;
typedef __attribute__((ext_vector_type(16))) float f32x16;

__device__ __forceinline__ u16 f2bf(float f){
  union { __hip_bfloat16 h; u16 u; } v; v.h = __float2bfloat16(f); return v.u;
}
__device__ __forceinline__ float bf2f(u16 h){
  union { uint32_t u; float f; } v; v.u = ((uint32_t)h) << 16;
  return v.f;
}
__device__ __forceinline__ f32x4 mfma16(short8 a, short8 b, f32x4 c){
  return __builtin_amdgcn_mfma_f32_16x16x32_bf16(a, b, c, 0, 0, 0);
}
__device__ __forceinline__ f32x16 mfma32(short8 a, short8 b, f32x16 c){
  return __builtin_amdgcn_mfma_f32_32x32x16_bf16(a, b, c, 0, 0, 0);
}
__device__ __forceinline__ void gl_lds16(const u16* g, u16* l){
  __builtin_amdgcn_global_load_lds((const __attribute__((address_space(1))) void*)g,
                                   (__attribute__((address_space(3))) void*)l, 16, 0, 0);
}
template<int N> __device__ __forceinline__ void waitvm(){
  if constexpr (N==0) asm volatile("s_waitcnt vmcnt(0)" ::: "memory");
  else if constexpr (N==2) asm volatile("s_waitcnt vmcnt(2)" ::: "memory");
  else if constexpr (N==4) asm volatile("s_waitcnt vmcnt(4)" ::: "memory");
  else if constexpr (N==8) asm volatile("s_waitcnt vmcnt(8)" ::: "memory");
  else static_assert(N==0 || N==2 || N==4 || N==8, "unsupported vmcnt");
}
__device__ __forceinline__ void phase_sep(){
  __builtin_amdgcn_sched_barrier(0);
  __builtin_amdgcn_s_barrier();
  __builtin_amdgcn_sched_barrier(0);
}
__device__ __forceinline__ uint32_t cvtpk(float lo, float hi){
  uint32_t r;
  asm("v_cvt_pk_bf16_f32 %0, %1, %2" : "=v"(r) : "v"(lo), "v"(hi));
  return r;
}

// ---------------- f32 -> bf16 convert (x) ----------------
__global__ __launch_bounds__(256) void cvt_x(const float* __restrict__ s,
                                             u16* __restrict__ d, int n4){
  const int i = blockIdx.x*256 + threadIdx.x;
  if (i >= n4) return;
  const float4 v = ((const float4*)s)[i];
  ushort4 pk;
  pk.x = f2bf(v.x); pk.y = f2bf(v.y); pk.z = f2bf(v.z); pk.w = f2bf(v.w);
  ((ushort4*)d)[i] = pk;
}

// ---------------- f32 [R][C] -> bf16 [C][R] transpose ----------------
__global__ __launch_bounds__(256) void transpose_cvt(const float* __restrict__ src,
    u16* __restrict__ dst, int R, int C)
{
  __shared__ float tile[32][33];
  const int tx = threadIdx.x, ty = threadIdx.y;
  const int c0 = blockIdx.x << 5, r0 = blockIdx.y << 5;
  #pragma unroll
  for (int i=0;i<4;i++)
    tile[ty + (i<<3)][tx] = src[(size_t)(r0 + ty + (i<<3))*C + c0 + tx];
  __syncthreads();
  #pragma unroll
  for (int i=0;i<4;i++)
    dst[(size_t)(c0 + ty + (i<<3))*R + r0 + tx] = f2bf(tile[tx][ty + (i<<3)]);
}

// ---------------- V transpose: qkv v-slice [S][128] -> vT [128][S] per (b,kv) ----------------
__global__ __launch_bounds__(256) void v_transpose(const u16* __restrict__ qkv,
    u16* __restrict__ vT)
{
  __shared__ u16 tile[32][33];
  const int tx = threadIdx.x, ty = threadIdx.y;
  const int s0 = blockIdx.x << 5, d0 = blockIdx.y << 5;
  const int bk = blockIdx.z; const int b = bk >> 2, kv = bk & 3;
  const u16* src = qkv + (size_t)b*2048*3072 + 2560 + kv*128;
  #pragma unroll
  for (int i=0;i<4;i++)
    tile[ty + (i<<3)][tx] = src[(size_t)(s0 + ty + (i<<3))*3072 + d0 + tx];
  __syncthreads();
  u16* dst = vT + (size_t)((b<<2)+kv)*128*2048;
  #pragma unroll
  for (int i=0;i<4;i++)
    dst[(size_t)(d0 + ty + (i<<3))*2048 + s0 + tx] = tile[tx][ty + (i<<3)];
}

// ---------------- RMSNorm over each 128-wide head row of q and k ----------------
// q heads additionally scaled by 1/sqrt(128)*log2(e) (softmax in exp2 domain).
__global__ __launch_bounds__(256) void rmsnorm_qk(u16* __restrict__ qkv,
    const float* __restrict__ qw, const float* __restrict__ kw)
{
  const int lane = threadIdx.x & 63;
  const int rid = blockIdx.x*4 + (threadIdx.x >> 6);   // 0..81919
  const int row = rid / 20;
  const int slot = rid % 20;                            // 0..15 q heads, 16..19 k heads
  u16* p = qkv + (size_t)row*3072 + slot*128 + (lane<<1);
  const u16 r0 = p[0], r1 = p[1];
  const float a = bf2f(r0), c = bf2f(r1);
  float ss = a*a + c*c;
  #pragma unroll
  for (int off=1; off<64; off<<=1) ss += __shfl_xor(ss, off);
  float sc = rsqrtf(ss*(1.0f/128.0f) + 1e-6f);
  if (slot < 16) sc *= 0.1275187952317199f;  // (1/sqrt(128)) * log2(e)
  const float* wp = (slot < 16) ? qw : kw;
  const float w0 = wp[lane<<1], w1 = wp[(lane<<1)+1];
  p[0] = f2bf(a*sc*w0);
  p[1] = f2bf(c*sc*w1);
}

// ---------------- 8-phase BMx256 bf16 GEMM: A[M][K] @ BT[N][K]^T -> C[M][ldc] ----
// BK=64, 8 waves (2M x 4N), 512 threads. LDS = 2 dbuf x {A0,A1,B0,B1}; A halves
// BM/2 rows, B halves 128 rows; XOR-involution layout. Snake quadrant order,
// counted vmcnt (leaves exactly the last A-stage in flight), setprio on MFMA.
// BM=256: 128KB LDS, vm wait 4.  BM=128: 96KB LDS, vm wait 2.
template<int BM, int CBF16>
__global__ __launch_bounds__(512, 2) void gemm8(const u16* __restrict__ A,
    const u16* __restrict__ BT, void* __restrict__ Cp,
    int M, int N, int K, int ldc)
{
  constexpr int MF   = BM/32;          // M-frags per wave
  constexpr int MQ   = MF/2;           // frags per quadrant phase
  constexpr int AH   = BM/2;           // rows per A half-slot
  constexpr int ASZ  = AH*64;          // u16 per A half-slot
  constexpr int DBUF = 2*ASZ + 16384;  // u16 per dbuf
  constexpr int WV   = (BM==256) ? 4 : 2;  // steady-state vmcnt
  __shared__ u16 lds[2*DBUF];
  const int tid = threadIdx.x;
  const int w = tid >> 6, lane = tid & 63;
  const int l15 = lane & 15, lg = lane >> 4;
  const int wm = w >> 2, wn = w & 3;
  const int nbx = N >> 8;
  const int nwg = gridDim.x;
  int bid = blockIdx.x;
  bid = (bid & 7) * (nwg >> 3) + (bid >> 3);   // bijective XCD swizzle (nwg%8==0)
  const int m0 = (bid / nbx) * BM;
  const int n0 = (bid % nbx) << 8;

  const u16* gA0 = A  + (size_t)m0*K;
  const u16* gA1 = gA0 + (size_t)AH*K;
  const u16* gB0 = BT + (size_t)n0*K;
  const u16* gB1 = gB0 + (size_t)128*K;

  auto slotA = [&](int d, int h)->u16*{ return lds + d*DBUF + h*ASZ; };
  auto slotB = [&](int d, int h)->u16*{ return lds + d*DBUF + 2*ASZ + h*8192; };

  // stage ROWS x 64k half-tile; linear unit p holds k-group (p&7)^(row&7) of row p>>3
  auto stage_half = [&](const u16* gbase, int kt, u16* sbase, int rows){
    const int iters = rows >> 6;               // rows*8/512
    for (int i=0;i<iters;i++){
      const int p = (i<<9) + tid;
      const int row = p>>3, sg = (p&7) ^ (row&7);
      gl_lds16(gbase + (size_t)row*K + (kt<<6) + (sg<<3), sbase + (p<<3));
    }
  };
  auto stA = [&](int kt, int d){ stage_half(gA0, kt, slotA(d,0), AH);
                                 stage_half(gA1, kt, slotA(d,1), AH); };
  auto stB = [&](int kt, int d){ stage_half(gB0, kt, slotB(d,0), 128);
                                 stage_half(gB1, kt, slotB(d,1), 128); };
  auto frag_at = [&](const u16* buf, int lrow, int kk)->short8{
    const int s = ((kk<<2)+lg) ^ (lrow&7);
    return *(const short8*)(buf + (((lrow<<3)+s)<<3));
  };

  short8 af[MQ][2], bfe[2][2], bfo[2][2];
  f32x4 acc[MF][4];
  #pragma unroll
  for (int m=0;m<MF;m++)
    #pragma unroll
    for (int n=0;n<4;n++) acc[m][n] = (f32x4){0.f,0.f,0.f,0.f};

  const int bh = wn>>1;                // my B-half index
  const int brow0 = ((wn&1)<<6) + l15; // base local row in B slot

  auto rd_a = [&](const u16* buf, int mq){
    #pragma unroll
    for (int m=0;m<MQ;m++)
      #pragma unroll
      for (int kk=0;kk<2;kk++)
        af[m][kk] = frag_at(buf, mq*(BM>>2) + (m<<4) + l15, kk);
  };
  auto rd_b = [&](const u16* buf, int nq, short8 (*dst)[2]){
    #pragma unroll
    for (int n=0;n<2;n++)
      #pragma unroll
      for (int kk=0;kk<2;kk++)
        dst[n][kk] = frag_at(buf, brow0 + (nq<<5) + (n<<4), kk);
  };
  auto do_mfma = [&](int mb, int nb, short8 (*bf)[2]){
    __builtin_amdgcn_s_setprio(1);
    #pragma unroll
    for (int m=0;m<MQ;m++)
      #pragma unroll
      for (int n=0;n<2;n++)
        #pragma unroll
        for (int kk=0;kk<2;kk++)
          acc[mb+m][nb+n] = mfma16(af[m][kk], bf[n][kk], acc[mb+m][nb+n]);
    __builtin_amdgcn_s_setprio(0);
  };

  stA(0,0); stB(0,0); stA(1,1);
  waitvm<WV>();
  phase_sep();

  const int niter = K >> 7;            // two K-tiles (BK=64) per iteration
  for (int i=0; i<niter; ++i){
    const bool full = (i+1 < niter);
    const int t1 = 2*i+1;
    rd_a(slotA(0,wm), 0); rd_b(slotB(0,bh), 0, bfe);
    stB(t1, 1);
    phase_sep();
    do_mfma(0, 0, bfe);
    phase_sep();
    rd_b(slotB(0,bh), 1, bfo);
    phase_sep();
    do_mfma(0, 2, bfo);
    phase_sep();
    rd_a(slotA(0,wm), 1);
    phase_sep();
    do_mfma(MQ, 2, bfo);
    phase_sep();
    rd_b(slotB(0,bh), 0, bfe);
    if (full) stA(t1+1, 0);
    phase_sep();
    do_mfma(MQ, 0, bfe);
    if (full) waitvm<WV>(); else waitvm<0>();
    phase_sep();
    rd_a(slotA(1,wm), 0); rd_b(slotB(1,bh), 0, bfe);
    if (full) stB(t1+1, 0);
    phase_sep();
    do_mfma(0, 0, bfe);
    phase_sep();
    rd_b(slotB(1,bh), 1, bfo);
    phase_sep();
    do_mfma(0, 2, bfo);
    phase_sep();
    rd_a(slotA(1,wm), 1);
    phase_sep();
    do_mfma(MQ, 2, bfo);
    phase_sep();
    rd_b(slotB(1,bh), 0, bfe);
    if (full) stA(t1+2, 1);
    phase_sep();
    do_mfma(MQ, 0, bfe);
    if (full) waitvm<WV>();
    phase_sep();
  }

  #pragma unroll
  for (int m=0;m<MF;m++){
    #pragma unroll
    for (int n=0;n<4;n++){
      const int col = n0 + (wn<<6) + (n<<4) + l15;
      #pragma unroll
      for (int r=0;r<4;r++){
        const int row = m0 + wm*AH + (m<<4) + (lg<<2) + r;
        if (CBF16) ((u16*)Cp)[(size_t)row*ldc + col] = f2bf(acc[m][n][r]);
        else       ((float*)Cp)[(size_t)row*ldc + col] = acc[m][n][r];
      }
    }
  }
}

// ---------------- causal GQA flash attention (R7 structure, known-good) ----------------
// grid (16,16,2), 256 threads / 4 waves; block owns one 128-row q-block
// (qI = b ? bx : 15-bx). 48 KB LDS (K dbuf + V) -> 2 blocks/CU. Counted vmcnt,
// 3 raw barriers/iter. P in-register via cvt_pk + permlane32_swap (T12).
__global__ __launch_bounds__(256, 2) void attn_kernel(const u16* __restrict__ qkv,
    const u16* __restrict__ vT, u16* __restrict__ aout)
{
  __shared__ u16 Klds[2][8192];   // [row 64][slot 16] 16B units, slot = d0 ^ (row&15)
  __shared__ u16 Vlds[8192];      // [rp=d/2][sl 16], sl = ((d&1)<<3 | k8) ^ (rp&15)
  const int tid = threadIdx.x;
  const int w = tid >> 6, lane = tid & 63;
  const int l31 = lane & 31, hi = lane >> 5;
  const int bx = blockIdx.x, h = blockIdx.y, b = blockIdx.z;
  const int qI = b ? bx : (15 - bx);
  const int kvh = h >> 2;
  const int qb = qI*128 + (w<<5);            // wave q-base (32 rows)
  const int nt = 2*qI + 2;

  const u16* qkvb = qkv + (size_t)b*2048*3072;
  short8 qf[8];
  {
    const u16* qp = qkvb + (size_t)(qb + l31)*3072 + h*128 + hi*8;
    #pragma unroll
    for (int kk=0;kk<8;kk++) qf[kk] = *(const short8*)(qp + kk*16);
  }
  f32x16 oacc[4];
  #pragma unroll
  for (int d=0;d<4;d++)
    #pragma unroll
    for (int r=0;r<16;r++) oacc[d][r] = 0.f;
  float m_run = -__builtin_inff(), lsum = 0.f;

  const u16* kb_ = qkvb + 2048 + kvh*128;
  const u16* vb_ = vT + (size_t)((b<<2)+kvh)*128*2048;

  auto stageK = [&](int t, int buf){
    #pragma unroll
    for (int i=0;i<4;i++){
      const int u = (i<<8) + tid;            // 0..1023
      const int row = u>>4, d0 = (u&15) ^ (row&15);
      gl_lds16(kb_ + (size_t)((t<<6)+row)*3072 + (d0<<3), &Klds[buf][u<<3]);
    }
  };
  auto stageV = [&](int t){
    #pragma unroll
    for (int i=0;i<4;i++){
      const int u = (i<<8) + tid;
      const int rp = u>>4, z = (u&15) ^ (rp&15);
      const int d = (rp<<1) + (z>>3), k8 = z&7;
      gl_lds16(vb_ + (size_t)d*2048 + (t<<6) + (k8<<3), &Vlds[u<<3]);
    }
  };

  stageK(0, 0);
  int kbuf = 0;
  for (int t=0; t<nt; ++t){
    const bool pre = (t+1 < nt);
    stageV(t);
    if (pre) stageK(t+1, kbuf^1);
    if (pre) waitvm<8>(); else waitvm<4>();  // K(t) landed, prefetches in flight
    phase_sep();
    const int t0 = t<<6;
    const bool act = (t0 <= qb + 31);        // wave-uniform
    uint32_t paw[4][4];
    if (act){
      // ---- S^T = K Q : lane holds 32 scores for q-row qb + l31
      f32x16 s0, s1;
      #pragma unroll
      for (int r=0;r<16;r++){ s0[r] = 0.f; s1[r] = 0.f; }
      #pragma unroll
      for (int kk=0;kk<8;kk++){
        const int d0 = (kk<<1) + hi;
        const short8 k0 = *(const short8*)&Klds[kbuf][((l31<<4) + (d0 ^ (l31&15)))<<3];
        s0 = mfma32(k0, qf[kk], s0);
        const int r1 = 32 + l31;
        const short8 k1 = *(const short8*)&Klds[kbuf][((r1<<4) + (d0 ^ (r1&15)))<<3];
        s1 = mfma32(k1, qf[kk], s1);
      }
      // ---- causal mask (k-local = (r&3)+8*(r>>2)+4*hi [+32])
      if (t0 + 63 > qb){
        const int qrel = qb + l31 - t0;
        #pragma unroll
        for (int r=0;r<16;r++){
          const int kloc = (r&3) + ((r>>2)<<3) + (hi<<2);
          if (kloc      > qrel) s0[r] = -__builtin_inff();
          if (kloc + 32 > qrel) s1[r] = -__builtin_inff();
        }
      }
      // ---- online softmax (defer-max, exp2 domain)
      float t8[8];
      #pragma unroll
      for (int i=0;i<8;i++) t8[i] = fmaxf(fmaxf(s0[i], s0[i+8]), fmaxf(s1[i], s1[i+8]));
      #pragma unroll
      for (int i=0;i<4;i++) t8[i] = fmaxf(t8[i], t8[i+4]);
      float mx = fmaxf(fmaxf(t8[0],t8[1]), fmaxf(t8[2],t8[3]));
      mx = fmaxf(mx, __shfl_xor(mx, 32));
      const bool noskip = !__all(mx - m_run <= 8.0f);
      const float mnew = noskip ? fmaxf(m_run, mx) : m_run;
      float rs = 0.f;
      #pragma unroll
      for (int i=0;i<16;i++){
        s0[i] = __builtin_amdgcn_exp2f(s0[i] - mnew);
        s1[i] = __builtin_amdgcn_exp2f(s1[i] - mnew);
        rs += s0[i] + s1[i];
      }
      rs += __shfl_xor(rs, 32);
      if (noskip){
        const float corr = __builtin_amdgcn_exp2f(m_run - mnew);
        m_run = mnew;
        lsum = lsum*corr + rs;
        #pragma unroll
        for (int r=0;r<16;r++){
          const float cr = __shfl(corr, (r&3) + ((r>>2)<<3) + (hi<<2));
          #pragma unroll
          for (int db=0;db<4;db++) oacc[db][r] *= cr;
        }
      } else {
        lsum += rs;
      }
      // ---- T12: PV A-frags in-register via cvt_pk + permlane32_swap
      #pragma unroll
      for (int kk=0;kk<4;kk++){
        const int base = (kk&1)<<3;
        float v0,v1,v2,v3,v4,v5,v6,v7;
        if (kk<2){ v0=s0[base+0]; v1=s0[base+1]; v2=s0[base+2]; v3=s0[base+3];
                   v4=s0[base+4]; v5=s0[base+5]; v6=s0[base+6]; v7=s0[base+7]; }
        else     { v0=s1[base+0]; v1=s1[base+1]; v2=s1[base+2]; v3=s1[base+3];
                   v4=s1[base+4]; v5=s1[base+5]; v6=s1[base+6]; v7=s1[base+7]; }
        uint32_t a0 = cvtpk(v0, v1), a1 = cvtpk(v2, v3);
        uint32_t b0 = cvtpk(v4, v5), b1 = cvtpk(v6, v7);
        asm volatile("v_permlane32_swap_b32 %0, %1" : "+v"(a0), "+v"(b0));
        asm volatile("v_permlane32_swap_b32 %0, %1" : "+v"(a1), "+v"(b1));
        paw[kk][0] = a0; paw[kk][1] = a1; paw[kk][2] = b0; paw[kk][3] = b1;
      }
    }
    if (pre) waitvm<4>(); else waitvm<0>();  // V(t) landed, K(t+1) in flight
    phase_sep();
    if (act){
      // ---- O += P V
      #pragma unroll
      for (int kk=0;kk<4;kk++){
        union { uint32_t w[4]; short8 v; } pu;
        pu.w[0]=paw[kk][0]; pu.w[1]=paw[kk][1]; pu.w[2]=paw[kk][2]; pu.w[3]=paw[kk][3];
        const short8 pa = pu.v;
        #pragma unroll
        for (int db=0;db<4;db++){
          const int d = (db<<5) + l31, rp = d>>1;
          const int sl = (((d&1)<<3) | ((kk<<1)+hi)) ^ (rp&15);
          const short8 vv = *(const short8*)&Vlds[((rp<<4)+sl)<<3];
          oacc[db] = mfma32(pa, vv, oacc[db]);
        }
      }
    }
    phase_sep();                             // PV reads done before next stageV
    kbuf ^= 1;
  }

  // ---- epilogue: normalize rows, store
  const float inv = 1.0f / lsum;
  #pragma unroll
  for (int r=0;r<16;r++){
    const int qr = (r&3) + ((r>>2)<<3) + (hi<<2);
    const float ivr = __shfl(inv, qr);
    u16* op = aout + (size_t)(b*2048 + qb + qr)*2048 + h*128 + l31;
    #pragma unroll
    for (int db=0;db<4;db++)
      op[db<<5] = f2bf(oacc[db][r] * ivr);
  }
}

extern "C" void kernel_launch(void* const* d_in, const int* in_sizes, int n_in,
                              void* d_out, int out_size, void* d_ws, size_t ws_size,
                              hipStream_t stream) {
  const float* x  = (const float*)d_in[0];
  const float* wq = (const float*)d_in[1];
  const float* wk = (const float*)d_in[2];
  const float* wv = (const float*)d_in[3];
  const float* wo = (const float*)d_in[4];
  const float* qw = (const float*)d_in[5];
  const float* kw = (const float*)d_in[6];
  char* ws = (char*)d_ws;
  u16* xbf   = (u16*)(ws);                 // 16 MB; reused as attn_out
  u16* wqkvT = (u16*)(ws + 16777216);      // 12 MB: [3072][2048] = wqT|wkT|wvT
  u16* woT   = (u16*)(ws + 29360128);      // 8 MB:  [2048][2048]
  u16* qkv   = (u16*)(ws + 37748736);      // 24 MB: [4096][3072] q|k|v
  u16* vT    = (u16*)(ws + 62914560);      // 4 MB:  [8][128][2048]
  float* out = (float*)d_out;

  dim3 tb(32,8);
  cvt_x<<<8192, 256, 0, stream>>>(x, xbf, 2097152);
  transpose_cvt<<<dim3(64,64), tb, 0, stream>>>(wq, wqkvT,             2048, 2048);
  transpose_cvt<<<dim3(16,64), tb, 0, stream>>>(wk, wqkvT + 2048*2048, 2048, 512);
  transpose_cvt<<<dim3(16,64), tb, 0, stream>>>(wv, wqkvT + 2560*2048, 2048, 512);
  transpose_cvt<<<dim3(64,64), tb, 0, stream>>>(wo, woT,               2048, 2048);
  gemm8<256,1><<<192, 512, 0, stream>>>(xbf, wqkvT, qkv, 4096, 3072, 2048, 3072);
  rmsnorm_qk<<<20480, 256, 0, stream>>>(qkv, qw, kw);
  v_transpose<<<dim3(64,4,8), tb, 0, stream>>>(qkv, vT);
  attn_kernel<<<dim3(16,16,2), 256, 0, stream>>>(qkv, vT, xbf);
  gemm8<128,0><<<256, 512, 0, stream>>>(xbf, woT, out, 4096, 2048, 2048, 2048);
}